// Round 4
// baseline (112.914 us; speedup 1.0000x reference)
//
#include <hip/hip_runtime.h>

#define BB 8
#define NN 2048
#define FF 128
#define RB 16
#define MT 128
#define PPAD 8

typedef short bh8 __attribute__((ext_vector_type(8)));
typedef float fl4 __attribute__((ext_vector_type(4)));
typedef unsigned short u16;

__device__ __forceinline__ u16 f2bf(float x) {
    unsigned u = __float_as_uint(x);
    return (u16)((u + 0x7FFFu + ((u >> 16) & 1u)) >> 16);
}

// ---------------------------------------------------------------------------
// kernel 1: h = feat @ W + b; store h as bf16 TRANSPOSED htg[b][o][n];
// e_src/e_dst side outputs; per-batch max(e_dst) via monotone-uint atomicMax.
// ---------------------------------------------------------------------------
__global__ __launch_bounds__(256) void k_h(
    const float* __restrict__ feat, const float* __restrict__ W,
    const float* __restrict__ bias, const float* __restrict__ a,
    u16* __restrict__ htg, float* __restrict__ esrc, float* __restrict__ edst,
    unsigned* __restrict__ gmaxu)
{
    __shared__ float fsh[8][FF];
    __shared__ float red[2][2][8];
    const int t = threadIdx.x;
    const long row0 = (long)blockIdx.x * 8;

    ((float4*)&fsh[0][0])[t] = ((const float4*)(feat + row0 * FF))[t];
    __syncthreads();

    const int o = t & 127;
    const int half = t >> 7;
    float acc[4] = {0.f, 0.f, 0.f, 0.f};
    #pragma unroll 4
    for (int k = 0; k < FF; ++k) {
        const float w = W[k * FF + o];
        #pragma unroll
        for (int r = 0; r < 4; ++r)
            acc[r] = fmaf(fsh[half * 4 + r][k], w, acc[r]);
    }
    const float bo = bias[o];
    const float as = a[o];
    const float ad = a[FF + o];
    float ps[4], pd[4];
    #pragma unroll
    for (int r = 0; r < 4; ++r) {
        acc[r] += bo;
        ps[r] = acc[r] * as;
        pd[r] = acc[r] * ad;
    }
    {
        const int bI = (int)(row0 >> 11);
        const int nloc = (int)(row0 & 2047) + half * 4;
        ushort4 hv;
        hv.x = f2bf(acc[0]); hv.y = f2bf(acc[1]);
        hv.z = f2bf(acc[2]); hv.w = f2bf(acc[3]);
        *(ushort4*)&htg[((long)bI * FF + o) * NN + nloc] = hv;
    }
    #pragma unroll
    for (int r = 0; r < 4; ++r) {
        #pragma unroll
        for (int off = 32; off > 0; off >>= 1) {
            ps[r] += __shfl_down(ps[r], off, 64);
            pd[r] += __shfl_down(pd[r], off, 64);
        }
    }
    const int wv = (t >> 6) & 1;
    if ((t & 63) == 0) {
        #pragma unroll
        for (int r = 0; r < 4; ++r) {
            red[half][wv][r]     = ps[r];
            red[half][wv][4 + r] = pd[r];
        }
    }
    __syncthreads();
    if (t < 16) {
        const int hh = t >> 3, idx = t & 7;
        const float v = red[hh][0][idx] + red[hh][1][idx];
        const long row = row0 + hh * 4 + (idx & 3);
        if (idx < 4) esrc[row] = v;
        else         edst[row] = v;
        // fused gmax: max over this block's 8 edst values -> 1 atomic
        float mv = (idx >= 4) ? v : -3.4e38f;
        #pragma unroll
        for (int off = 8; off > 0; off >>= 1)
            mv = fmaxf(mv, __shfl_xor(mv, off, 16));
        if (t == 0) {
            unsigned bu = __float_as_uint(mv);
            bu = (bu & 0x80000000u) ? ~bu : (bu | 0x80000000u);
            atomicMax(gmaxu + (int)(row0 >> 11), bu);
        }
    }
}

// ---------------------------------------------------------------------------
// kernel 2: 256 threads (4 waves, one 16-row P tile, col quarter per wave).
// Double-buffered bf16 P in LDS, one lgkm-only raw barrier per m-tile.
// adj/edst prefetched TWO tiles ahead (named-reg rotation); bfrags issued at
// loop top (before prefetch) so the bfrag vmcnt wait leaves prefetch in flight.
// ---------------------------------------------------------------------------
__global__ __launch_bounds__(256, 4) void k_attn(
    const int* __restrict__ adj, const float* __restrict__ mask,
    const u16* __restrict__ htg, const float* __restrict__ esrc,
    const float* __restrict__ edst, const unsigned* __restrict__ gmaxu,
    float* __restrict__ out)
{
    __shared__ u16 p_sh[2][RB][MT + PPAD];
    __shared__ float psum_sh[RB];

    const int t = threadIdx.x;
    const int b = blockIdx.x & 7;               // batch -> XCD affinity
    const int n0 = (blockIdx.x >> 3) * RB;      // 128 tiles per batch

    // phase-A mapping: thread covers rows {pr0, pr0+1}, m = lane31*4..+3
    const int lane31 = t & 31;
    const int pr0 = (t >> 5) * 2;
    const long adjbase = (long)b * NN * NN + (long)(n0 + pr0) * NN;

    const float es0 = esrc[b * NN + n0 + pr0];
    const float es1 = esrc[b * NN + n0 + pr0 + 1];
    const unsigned gu = gmaxu[b];
    const float gm = __uint_as_float((gu & 0x80000000u) ? (gu & 0x7FFFFFFFu) : ~gu);
    const float t0 = es0 + gm; const float M0 = (t0 >= 0.f) ? t0 : 0.01f * t0;
    const float t1 = es1 + gm; const float M1 = (t1 >= 0.f) ? t1 : 0.01f * t1;

    // MFMA mapping: wave w covers cols w*32..w*32+31
    const int w = t >> 6, lane = t & 63;
    const int c0 = w * 32;
    const int lr = lane & 15, g = lane >> 4;
    const u16* hB = htg + (long)b * FF * NN;

    fl4 acc0 = (fl4){0.f, 0.f, 0.f, 0.f};
    fl4 acc1 = (fl4){0.f, 0.f, 0.f, 0.f};
    float psum0 = 0.f, psum1 = 0.f;

    // 2-deep prefetch pipeline (named regs; no runtime-indexed arrays)
    int4 adjA0 = *(const int4*)(adj + adjbase + lane31 * 4);
    int4 adjA1 = *(const int4*)(adj + adjbase + NN + lane31 * 4);
    float4 edvA = *(const float4*)(edst + b * NN + lane31 * 4);
    int4 adjB0 = *(const int4*)(adj + adjbase + MT + lane31 * 4);
    int4 adjB1 = *(const int4*)(adj + adjbase + NN + MT + lane31 * 4);
    float4 edvB = *(const float4*)(edst + b * NN + MT + lane31 * 4);

    int cur = 0;
    for (int m0 = 0; m0 < NN; m0 += MT) {
        // B-fragment loads for this tile (issued FIRST -> their vmcnt wait
        // does not drain the adj prefetch issued below)
        bh8 bfrag[4][2];
        #pragma unroll
        for (int kc = 0; kc < 4; ++kc)
            #pragma unroll
            for (int ct = 0; ct < 2; ++ct)
                bfrag[kc][ct] = *(const bh8*)(hB + (long)(c0 + ct * 16 + lr) * NN
                                              + m0 + kc * 32 + g * 8);

        // phase A: P rows pr0/pr0+1 from regs prefetched 2 tiles ago
        {
            const float edf[4] = {edvA.x, edvA.y, edvA.z, edvA.w};
            const int a0[4] = {adjA0.x, adjA0.y, adjA0.z, adjA0.w};
            const int a1[4] = {adjA1.x, adjA1.y, adjA1.z, adjA1.w};
            u16 pb0[4], pb1[4];
            #pragma unroll
            for (int j = 0; j < 4; ++j) {
                float x0 = es0 + edf[j]; x0 = (x0 >= 0.f) ? x0 : 0.01f * x0;
                float x1 = es1 + edf[j]; x1 = (x1 >= 0.f) ? x1 : 0.01f * x1;
                const float p0 = (a0[j] > 0) ? __expf(x0 - M0) : 0.f;
                const float p1 = (a1[j] > 0) ? __expf(x1 - M1) : 0.f;
                const u16 u0 = f2bf(p0), u1 = f2bf(p1);
                pb0[j] = u0; pb1[j] = u1;
                psum0 += __uint_as_float((unsigned)u0 << 16);
                psum1 += __uint_as_float((unsigned)u1 << 16);
            }
            *(ushort4*)&p_sh[cur][pr0][lane31 * 4]     = make_ushort4(pb0[0], pb0[1], pb0[2], pb0[3]);
            *(ushort4*)&p_sh[cur][pr0 + 1][lane31 * 4] = make_ushort4(pb1[0], pb1[1], pb1[2], pb1[3]);
        }

        // issue prefetch for tile m0 + 2*MT
        {
            const int mn = (m0 + 2 * MT < NN) ? (m0 + 2 * MT) : 0;
            adjA0 = adjB0; adjA1 = adjB1; edvA = edvB;
            adjB0 = *(const int4*)(adj + adjbase + mn + lane31 * 4);
            adjB1 = *(const int4*)(adj + adjbase + NN + mn + lane31 * 4);
            edvB  = *(const float4*)(edst + b * NN + mn + lane31 * 4);
        }

        // publish P tile: drain LDS writes only; vmcnt stays outstanding
        asm volatile("s_waitcnt lgkmcnt(0)" ::: "memory");
        __builtin_amdgcn_s_barrier();
        asm volatile("" ::: "memory");

        #pragma unroll
        for (int kc = 0; kc < 4; ++kc) {
            const bh8 afrag = *(const bh8*)&p_sh[cur][lr][kc * 32 + g * 8];
            acc0 = __builtin_amdgcn_mfma_f32_16x16x32_bf16(afrag, bfrag[kc][0], acc0, 0, 0, 0);
            acc1 = __builtin_amdgcn_mfma_f32_16x16x32_bf16(afrag, bfrag[kc][1], acc1, 0, 0, 0);
        }
        cur ^= 1;
    }

    // psum reduce within each 32-lane group (rows pr0, pr0+1)
    #pragma unroll
    for (int off = 16; off > 0; off >>= 1) {
        psum0 += __shfl_down(psum0, off, 32);
        psum1 += __shfl_down(psum1, off, 32);
    }
    if (lane31 == 0) { psum_sh[pr0] = psum0; psum_sh[pr0 + 1] = psum1; }
    __syncthreads();

    // epilogue: C/D layout col=lane&15, row=(lane>>4)*4+reg  [m89/m91]
    const long obase = ((long)b * NN + n0) * FF;
    #pragma unroll
    for (int reg = 0; reg < 4; ++reg) {
        const int rowin = g * 4 + reg;
        const float s = mask[b * NN + n0 + rowin] / psum_sh[rowin];
        out[obase + (long)rowin * FF + c0 + lr]      = acc0[reg] * s;
        out[obase + (long)rowin * FF + c0 + 16 + lr] = acc1[reg] * s;
    }
}

// ---------------------------------------------------------------------------
extern "C" void kernel_launch(void* const* d_in, const int* in_sizes, int n_in,
                              void* d_out, int out_size, void* d_ws, size_t ws_size,
                              hipStream_t stream)
{
    const float* feat = (const float*)d_in[0];
    const int*   adj  = (const int*)d_in[1];
    const float* mask = (const float*)d_in[2];
    const float* W    = (const float*)d_in[3];
    const float* bias = (const float*)d_in[4];
    const float* a    = (const float*)d_in[5];
    float* out = (float*)d_out;

    // ws: htg bf16 [8][128][2048] (4MB) | esrc f32 | edst f32 | gmaxu u32[8]
    u16*   htg  = (u16*)d_ws;
    float* esrc = (float*)(htg + (size_t)BB * FF * NN);
    float* edst = esrc + BB * NN;
    unsigned* gmaxu = (unsigned*)(edst + BB * NN);

    hipMemsetAsync(gmaxu, 0, BB * sizeof(unsigned), stream);
    k_h   <<<BB * NN / 8, 256, 0, stream>>>(feat, W, bias, a, htg, esrc, edst, gmaxu);
    k_attn<<<BB * (NN / RB), 256, 0, stream>>>(adj, mask, htg, esrc, edst, gmaxu, out);
}

// Round 5
// 103.283 us; speedup vs baseline: 1.0933x; 1.0933x over previous
//
#include <hip/hip_runtime.h>

#define BB 8
#define NN 2048
#define FF 128
#define RB 16
#define MT 128

typedef short bh8 __attribute__((ext_vector_type(8)));
typedef float fl4 __attribute__((ext_vector_type(4)));
typedef unsigned short u16;

__device__ __forceinline__ u16 f2bf(float x) {
    unsigned u = __float_as_uint(x);
    return (u16)((u + 0x7FFFu + ((u >> 16) & 1u)) >> 16);
}

// ---------------------------------------------------------------------------
// kernel 1: h = feat @ W + b; store h as bf16 TRANSPOSED htg[b][o][n];
// also e_src = h@a[:128], e_dst = h@a[128:]. 8 rows per 256-thread block.
// ---------------------------------------------------------------------------
__global__ __launch_bounds__(256) void k_h(
    const float* __restrict__ feat, const float* __restrict__ W,
    const float* __restrict__ bias, const float* __restrict__ a,
    u16* __restrict__ htg, float* __restrict__ esrc, float* __restrict__ edst)
{
    __shared__ float fsh[8][FF];
    __shared__ float red[2][2][8];
    const int t = threadIdx.x;
    const long row0 = (long)blockIdx.x * 8;

    ((float4*)&fsh[0][0])[t] = ((const float4*)(feat + row0 * FF))[t];
    __syncthreads();

    const int o = t & 127;
    const int half = t >> 7;
    float acc[4] = {0.f, 0.f, 0.f, 0.f};
    #pragma unroll 4
    for (int k = 0; k < FF; ++k) {
        const float w = W[k * FF + o];
        #pragma unroll
        for (int r = 0; r < 4; ++r)
            acc[r] = fmaf(fsh[half * 4 + r][k], w, acc[r]);
    }
    const float bo = bias[o];
    const float as = a[o];
    const float ad = a[FF + o];
    float ps[4], pd[4];
    #pragma unroll
    for (int r = 0; r < 4; ++r) {
        acc[r] += bo;
        ps[r] = acc[r] * as;
        pd[r] = acc[r] * ad;
    }
    {
        const int bI = (int)(row0 >> 11);
        const int nloc = (int)(row0 & 2047) + half * 4;
        ushort4 hv;
        hv.x = f2bf(acc[0]); hv.y = f2bf(acc[1]);
        hv.z = f2bf(acc[2]); hv.w = f2bf(acc[3]);
        *(ushort4*)&htg[((long)bI * FF + o) * NN + nloc] = hv;
    }
    #pragma unroll
    for (int r = 0; r < 4; ++r) {
        #pragma unroll
        for (int off = 32; off > 0; off >>= 1) {
            ps[r] += __shfl_down(ps[r], off, 64);
            pd[r] += __shfl_down(pd[r], off, 64);
        }
    }
    const int wv = (t >> 6) & 1;
    if ((t & 63) == 0) {
        #pragma unroll
        for (int r = 0; r < 4; ++r) {
            red[half][wv][r]     = ps[r];
            red[half][wv][4 + r] = pd[r];
        }
    }
    __syncthreads();
    if (t < 16) {
        const int hh = t >> 3, idx = t & 7;
        const float v = red[hh][0][idx] + red[hh][1][idx];
        const long row = row0 + hh * 4 + (idx & 3);
        if (idx < 4) esrc[row] = v;
        else         edst[row] = v;
    }
}

// ---------------------------------------------------------------------------
// kernel 2: barrier-free main loop. Block = 4 waves, one 16-row tile.
// Wave w owns m-tiles {w, w+4, w+8, w+12}; computes its P fragments entirely
// in registers (lane (lr,g) computes P[lr][m0+kc*32+g*8+e], e=0..7 — exactly
// its MFMA A-fragment), accumulates partial 16x128 output. One final barrier +
// 32KB LDS reduction combines the 4 m-partials. gmax computed per-wave inline.
// ---------------------------------------------------------------------------
__global__ __launch_bounds__(256, 4) void k_attn(
    const int* __restrict__ adj, const float* __restrict__ mask,
    const u16* __restrict__ htg, const float* __restrict__ esrc,
    const float* __restrict__ edst, float* __restrict__ out)
{
    __shared__ float accbuf[4][RB][FF];   // 32 KB
    __shared__ float psum_sh[4][RB];

    const int t = threadIdx.x;
    const int b = blockIdx.x & 7;               // batch -> XCD affinity
    const int n0 = (blockIdx.x >> 3) * RB;      // 128 tiles per batch
    const int w = t >> 6, lane = t & 63;
    const int lr = lane & 15, g = lane >> 4;

    // per-wave gmax over edst[b][:] (2048 floats, L2-hot; no cross-wave sync)
    float gmx = -3.4e38f;
    {
        const float4* edp = (const float4*)(edst + b * NN);
        #pragma unroll
        for (int i = 0; i < 8; ++i) {
            const float4 v = edp[lane + 64 * i];
            gmx = fmaxf(gmx, fmaxf(fmaxf(v.x, v.y), fmaxf(v.z, v.w)));
        }
        #pragma unroll
        for (int off = 32; off > 0; off >>= 1)
            gmx = fmaxf(gmx, __shfl_xor(gmx, off, 64));
    }

    const float es = esrc[b * NN + n0 + lr];
    const float tM = es + gmx;
    const float M = (tM >= 0.f) ? tM : 0.01f * tM;   // leaky(es+gmax) >= rowmax

    const long adjrow = (long)b * NN * NN + (long)(n0 + lr) * NN;
    const u16* hB = htg + (long)b * FF * NN;
    const float* edb = edst + b * NN;

    fl4 acc[8];
    #pragma unroll
    for (int ct = 0; ct < 8; ++ct) acc[ct] = (fl4){0.f, 0.f, 0.f, 0.f};
    float psum = 0.f;

    #pragma unroll 1
    for (int it = 0; it < 4; ++it) {
        const int m0 = (w + 4 * it) * MT;
        const int base = m0 + g * 8;

        // adjacency for this lane's A-fragment rows/cols: 8 ints per kc
        int4 aj[8];
        #pragma unroll
        for (int kc = 0; kc < 4; ++kc) {
            aj[2 * kc]     = *(const int4*)(adj + adjrow + base + kc * 32);
            aj[2 * kc + 1] = *(const int4*)(adj + adjrow + base + kc * 32 + 4);
        }

        // build A-fragments in-register (P = adj ? exp(leaky(es+ed)-M) : 0)
        bh8 af[4];
        #pragma unroll
        for (int kc = 0; kc < 4; ++kc) {
            const float4 e0 = *(const float4*)(edb + base + kc * 32);
            const float4 e1 = *(const float4*)(edb + base + kc * 32 + 4);
            const float ee[8] = {e0.x, e0.y, e0.z, e0.w, e1.x, e1.y, e1.z, e1.w};
            const int   aa[8] = {aj[2*kc].x, aj[2*kc].y, aj[2*kc].z, aj[2*kc].w,
                                 aj[2*kc+1].x, aj[2*kc+1].y, aj[2*kc+1].z, aj[2*kc+1].w};
            u16 pb[8];
            #pragma unroll
            for (int j = 0; j < 8; ++j) {
                float x = es + ee[j];
                x = (x >= 0.f) ? x : 0.01f * x;
                const float p = (aa[j] > 0) ? __expf(x - M) : 0.f;
                const u16 ub = f2bf(p);
                pb[j] = ub;
                // accumulate ROUNDED value -> numerator/denominator consistent
                psum += __uint_as_float((unsigned)ub << 16);
            }
            af[kc] = (bh8){(short)pb[0], (short)pb[1], (short)pb[2], (short)pb[3],
                           (short)pb[4], (short)pb[5], (short)pb[6], (short)pb[7]};
        }

        // MFMA: acc[ct] += af[kc] * H[ct-tile]
        #pragma unroll
        for (int kc = 0; kc < 4; ++kc) {
            #pragma unroll
            for (int ct = 0; ct < 8; ++ct) {
                const bh8 bf = *(const bh8*)(hB + (long)(ct * 16 + lr) * NN + base + kc * 32);
                acc[ct] = __builtin_amdgcn_mfma_f32_16x16x32_bf16(af[kc], bf, acc[ct], 0, 0, 0);
            }
        }
    }

    // combine partials: psum across g-groups (lanes lr, lr+16, lr+32, lr+48)
    psum += __shfl_xor(psum, 16, 64);
    psum += __shfl_xor(psum, 32, 64);
    if (lane < 16) psum_sh[w][lane] = psum;

    // C/D layout: col = ct*16 + (lane&15), row = (lane>>4)*4 + reg  [m89/m91]
    #pragma unroll
    for (int ct = 0; ct < 8; ++ct)
        #pragma unroll
        for (int reg = 0; reg < 4; ++reg)
            accbuf[w][g * 4 + reg][ct * 16 + lr] = acc[ct][reg];
    __syncthreads();

    // epilogue: sum 4 wave-partials, scale, write. 512 float4 / 256 threads.
    #pragma unroll
    for (int rep = 0; rep < 2; ++rep) {
        const int idx = t + 256 * rep;
        const int r = idx >> 5;               // 32 float4 per row
        const int c4 = (idx & 31) * 4;
        const float4 s0 = *(const float4*)&accbuf[0][r][c4];
        const float4 s1 = *(const float4*)&accbuf[1][r][c4];
        const float4 s2 = *(const float4*)&accbuf[2][r][c4];
        const float4 s3 = *(const float4*)&accbuf[3][r][c4];
        const float ps = psum_sh[0][r] + psum_sh[1][r] + psum_sh[2][r] + psum_sh[3][r];
        const float sc = mask[b * NN + n0 + r] / ps;
        float4 o;
        o.x = (s0.x + s1.x + s2.x + s3.x) * sc;
        o.y = (s0.y + s1.y + s2.y + s3.y) * sc;
        o.z = (s0.z + s1.z + s2.z + s3.z) * sc;
        o.w = (s0.w + s1.w + s2.w + s3.w) * sc;
        *(float4*)&out[((long)b * NN + n0 + r) * FF + c4] = o;
    }
}

// ---------------------------------------------------------------------------
extern "C" void kernel_launch(void* const* d_in, const int* in_sizes, int n_in,
                              void* d_out, int out_size, void* d_ws, size_t ws_size,
                              hipStream_t stream)
{
    const float* feat = (const float*)d_in[0];
    const int*   adj  = (const int*)d_in[1];
    const float* mask = (const float*)d_in[2];
    const float* W    = (const float*)d_in[3];
    const float* bias = (const float*)d_in[4];
    const float* a    = (const float*)d_in[5];
    float* out = (float*)d_out;

    // ws: htg bf16 [8][128][2048] (4MB) | esrc f32 | edst f32
    u16*   htg  = (u16*)d_ws;
    float* esrc = (float*)(htg + (size_t)BB * FF * NN);
    float* edst = esrc + BB * NN;

    k_h   <<<BB * NN / 8, 256, 0, stream>>>(feat, W, bias, a, htg, esrc, edst);
    k_attn<<<BB * (NN / RB), 256, 0, stream>>>(adj, mask, htg, esrc, edst, out);
}

// Round 6
// 86.151 us; speedup vs baseline: 1.3107x; 1.1989x over previous
//
#include <hip/hip_runtime.h>

#define BB 8
#define NN 2048
#define FF 128
#define RB 32
#define MT 128

typedef short bh8 __attribute__((ext_vector_type(8)));
typedef float fl4 __attribute__((ext_vector_type(4)));
typedef unsigned short u16;
typedef unsigned long long u64;

__device__ __forceinline__ u16 f2bf(float x) {
    unsigned u = __float_as_uint(x);
    return (u16)((u + 0x7FFFu + ((u >> 16) & 1u)) >> 16);
}

// ---------------------------------------------------------------------------
// kernel 1: h = feat @ W + b; store h as bf16 TRANSPOSED htg[b][o][n];
// also e_src = h@a[:128], e_dst = h@a[128:]. 8 rows per 256-thread block.
// ---------------------------------------------------------------------------
__global__ __launch_bounds__(256) void k_h(
    const float* __restrict__ feat, const float* __restrict__ W,
    const float* __restrict__ bias, const float* __restrict__ a,
    u16* __restrict__ htg, float* __restrict__ esrc, float* __restrict__ edst)
{
    __shared__ float fsh[8][FF];
    __shared__ float red[2][2][8];
    const int t = threadIdx.x;
    const long row0 = (long)blockIdx.x * 8;

    ((float4*)&fsh[0][0])[t] = ((const float4*)(feat + row0 * FF))[t];
    __syncthreads();

    const int o = t & 127;
    const int half = t >> 7;
    float acc[4] = {0.f, 0.f, 0.f, 0.f};
    #pragma unroll 4
    for (int k = 0; k < FF; ++k) {
        const float w = W[k * FF + o];
        #pragma unroll
        for (int r = 0; r < 4; ++r)
            acc[r] = fmaf(fsh[half * 4 + r][k], w, acc[r]);
    }
    const float bo = bias[o];
    const float as = a[o];
    const float ad = a[FF + o];
    float ps[4], pd[4];
    #pragma unroll
    for (int r = 0; r < 4; ++r) {
        acc[r] += bo;
        ps[r] = acc[r] * as;
        pd[r] = acc[r] * ad;
    }
    {
        const int bI = (int)(row0 >> 11);
        const int nloc = (int)(row0 & 2047) + half * 4;
        ushort4 hv;
        hv.x = f2bf(acc[0]); hv.y = f2bf(acc[1]);
        hv.z = f2bf(acc[2]); hv.w = f2bf(acc[3]);
        *(ushort4*)&htg[((long)bI * FF + o) * NN + nloc] = hv;
    }
    #pragma unroll
    for (int r = 0; r < 4; ++r) {
        #pragma unroll
        for (int off = 32; off > 0; off >>= 1) {
            ps[r] += __shfl_down(ps[r], off, 64);
            pd[r] += __shfl_down(pd[r], off, 64);
        }
    }
    const int wv = (t >> 6) & 1;
    if ((t & 63) == 0) {
        #pragma unroll
        for (int r = 0; r < 4; ++r) {
            red[half][wv][r]     = ps[r];
            red[half][wv][4 + r] = pd[r];
        }
    }
    __syncthreads();
    if (t < 16) {
        const int hh = t >> 3, idx = t & 7;
        const float v = red[hh][0][idx] + red[hh][1][idx];
        const long row = row0 + hh * 4 + (idx & 3);
        if (idx < 4) esrc[row] = v;
        else         edst[row] = v;
    }
}

// ---------------------------------------------------------------------------
// kernel 2: pack adjacency into a bitmask (bit j of byte i of row == adj col
// 8i+j). Pure coalesced stream: 134 MB read -> 4 MB write. 8 rows per block.
// ---------------------------------------------------------------------------
__global__ __launch_bounds__(256) void k_pack(
    const int* __restrict__ adj, u64* __restrict__ bm)
{
    const int t = threadIdx.x;
    const int w = t >> 6, lane = t & 63;
    const long row0 = (long)blockIdx.x * 8;
    // wave w packs rows 2w, 2w+1; each row = 32 chunks of 64 cols
    #pragma unroll 8
    for (int i = 0; i < 64; ++i) {
        const int row = 2 * w + (i >> 5);
        const int chunk = i & 31;
        const int av = adj[(row0 + row) * NN + chunk * 64 + lane];
        const u64 m64 = __ballot(av > 0);
        if (lane == 0) bm[(row0 + row) * 32 + chunk] = m64;
    }
}

// ---------------------------------------------------------------------------
// kernel 3: block = 32 rows, 4 waves, m-split 4 (wave w owns tiles w+4*it).
// All operands L2-resident (bm 4MB, htg 4MB, edst 8KB/batch). Lane (lr,g)
// builds P[lr][.] and P[lr+16][.] A-fragments in registers from the bitmask,
// 16 MFMAs per kc reuse each B-fragment twice. bm prefetched 1 iter ahead,
// bf double-buffered 1 kc ahead. Final LDS reduce combines 4 m-partials.
// ---------------------------------------------------------------------------
__global__ __launch_bounds__(256, 2) void k_attn(
    const u64* __restrict__ bm, const float* __restrict__ mask,
    const u16* __restrict__ htg, const float* __restrict__ esrc,
    const float* __restrict__ edst, float* __restrict__ out)
{
    __shared__ float accbuf[4][RB][FF + 4];   // ~67.6 KB
    __shared__ float psum_sh[4][RB];

    const int t = threadIdx.x;
    const int b = blockIdx.x & 7;               // batch -> XCD affinity
    const int n0 = (blockIdx.x >> 3) * RB;      // 64 tiles per batch
    const int w = t >> 6, lane = t & 63;
    const int lr = lane & 15, g = lane >> 4;

    // per-wave gmax over edst[b][:] (8 KB, L2-hot)
    float gmx = -3.4e38f;
    {
        const float4* edp = (const float4*)(edst + b * NN);
        #pragma unroll
        for (int i = 0; i < 8; ++i) {
            const float4 v = edp[lane + 64 * i];
            gmx = fmaxf(gmx, fmaxf(fmaxf(v.x, v.y), fmaxf(v.z, v.w)));
        }
        #pragma unroll
        for (int off = 32; off > 0; off >>= 1)
            gmx = fmaxf(gmx, __shfl_xor(gmx, off, 64));
    }

    const float es0 = esrc[b * NN + n0 + lr];
    const float es1 = esrc[b * NN + n0 + 16 + lr];
    const float tA = es0 + gmx; const float M0 = (tA >= 0.f) ? tA : 0.01f * tA;
    const float tB = es1 + gmx; const float M1 = (tB >= 0.f) ? tB : 0.01f * tB;

    const uint4* bmb = (const uint4*)(bm + ((long)b * NN + n0) * 32);
    const float* edb = edst + b * NN;
    const u16* hB = htg + (long)b * FF * NN;

    fl4 acc0[8], acc1[8];
    #pragma unroll
    for (int ct = 0; ct < 8; ++ct) {
        acc0[ct] = (fl4){0.f, 0.f, 0.f, 0.f};
        acc1[ct] = (fl4){0.f, 0.f, 0.f, 0.f};
    }
    float psum0 = 0.f, psum1 = 0.f;

    // prologue: bitmask prefetch for it=0 (row lr and lr+16, uint4 = 128 cols)
    uint4 bmA0 = bmb[lr * 16 + w];
    uint4 bmA1 = bmb[(16 + lr) * 16 + w];

    #pragma unroll 1
    for (int it = 0; it < 4; ++it) {
        const int m0 = (w + 4 * it) * MT;
        const int base = m0 + g * 8;

        // 1) issue edst loads (af-build waits on these; rest stays in flight)
        float4 ed[8];
        #pragma unroll
        for (int kc = 0; kc < 4; ++kc) {
            ed[2 * kc]     = *(const float4*)(edb + base + kc * 32);
            ed[2 * kc + 1] = *(const float4*)(edb + base + kc * 32 + 4);
        }
        // 2) issue B-fragments for kc=0
        bh8 bfA[8];
        #pragma unroll
        for (int ct = 0; ct < 8; ++ct)
            bfA[ct] = *(const bh8*)(hB + (long)(ct * 16 + lr) * NN + base);
        // 3) issue next iteration's bitmask prefetch
        const int itn = (it + 1) & 3;
        uint4 bmB0 = bmb[lr * 16 + w + 4 * itn];
        uint4 bmB1 = bmb[(16 + lr) * 16 + w + 4 * itn];

        // 4) build both A-fragment sets in registers
        bh8 af0[4], af1[4];
        #pragma unroll
        for (int kc = 0; kc < 4; ++kc) {
            const unsigned w0 = (kc == 0) ? bmA0.x : (kc == 1) ? bmA0.y
                              : (kc == 2) ? bmA0.z : bmA0.w;
            const unsigned w1 = (kc == 0) ? bmA1.x : (kc == 1) ? bmA1.y
                              : (kc == 2) ? bmA1.z : bmA1.w;
            const unsigned by0 = (w0 >> (8 * g)) & 0xFFu;
            const unsigned by1 = (w1 >> (8 * g)) & 0xFFu;
            const float4 e0 = ed[2 * kc], e1 = ed[2 * kc + 1];
            const float ee[8] = {e0.x, e0.y, e0.z, e0.w, e1.x, e1.y, e1.z, e1.w};
            u16 p0[8], p1[8];
            #pragma unroll
            for (int j = 0; j < 8; ++j) {
                float x0 = es0 + ee[j]; x0 = (x0 >= 0.f) ? x0 : 0.01f * x0;
                float x1 = es1 + ee[j]; x1 = (x1 >= 0.f) ? x1 : 0.01f * x1;
                const float v0 = ((by0 >> j) & 1u) ? __expf(x0 - M0) : 0.f;
                const float v1 = ((by1 >> j) & 1u) ? __expf(x1 - M1) : 0.f;
                const u16 u0 = f2bf(v0), u1 = f2bf(v1);
                p0[j] = u0; p1[j] = u1;
                // accumulate ROUNDED values -> num/denom consistent
                psum0 += __uint_as_float((unsigned)u0 << 16);
                psum1 += __uint_as_float((unsigned)u1 << 16);
            }
            af0[kc] = (bh8){(short)p0[0], (short)p0[1], (short)p0[2], (short)p0[3],
                            (short)p0[4], (short)p0[5], (short)p0[6], (short)p0[7]};
            af1[kc] = (bh8){(short)p1[0], (short)p1[1], (short)p1[2], (short)p1[3],
                            (short)p1[4], (short)p1[5], (short)p1[6], (short)p1[7]};
        }

        // 5) kc loop: bf double-buffered one step ahead, 16 MFMAs per kc
        #pragma unroll
        for (int kc = 0; kc < 4; ++kc) {
            bh8 bfB[8];
            if (kc < 3) {
                #pragma unroll
                for (int ct = 0; ct < 8; ++ct)
                    bfB[ct] = *(const bh8*)(hB + (long)(ct * 16 + lr) * NN
                                            + base + (kc + 1) * 32);
            }
            #pragma unroll
            for (int ct = 0; ct < 8; ++ct) {
                acc0[ct] = __builtin_amdgcn_mfma_f32_16x16x32_bf16(af0[kc], bfA[ct], acc0[ct], 0, 0, 0);
                acc1[ct] = __builtin_amdgcn_mfma_f32_16x16x32_bf16(af1[kc], bfA[ct], acc1[ct], 0, 0, 0);
            }
            if (kc < 3) {
                #pragma unroll
                for (int ct = 0; ct < 8; ++ct) bfA[ct] = bfB[ct];
            }
        }
        bmA0 = bmB0; bmA1 = bmB1;
    }

    // psum: rows lr / lr+16 partials live in lanes {lr, lr+16, lr+32, lr+48}
    psum0 += __shfl_xor(psum0, 16, 64);
    psum0 += __shfl_xor(psum0, 32, 64);
    psum1 += __shfl_xor(psum1, 16, 64);
    psum1 += __shfl_xor(psum1, 32, 64);
    if (lane < 16) {
        psum_sh[w][lr] = psum0;
        psum_sh[w][16 + lr] = psum1;
    }

    // C/D layout: col = ct*16 + (lane&15), row = (lane>>4)*4 + reg  [m89/m91]
    #pragma unroll
    for (int ct = 0; ct < 8; ++ct)
        #pragma unroll
        for (int reg = 0; reg < 4; ++reg) {
            accbuf[w][g * 4 + reg][ct * 16 + lr]      = acc0[ct][reg];
            accbuf[w][16 + g * 4 + reg][ct * 16 + lr] = acc1[ct][reg];
        }
    __syncthreads();

    // epilogue: sum 4 wave-partials, scale, write. 1024 float4 / 256 threads.
    #pragma unroll
    for (int rep = 0; rep < 4; ++rep) {
        const int idx = t + 256 * rep;
        const int r = idx >> 5;
        const int c4 = (idx & 31) * 4;
        const float4 s0 = *(const float4*)&accbuf[0][r][c4];
        const float4 s1 = *(const float4*)&accbuf[1][r][c4];
        const float4 s2 = *(const float4*)&accbuf[2][r][c4];
        const float4 s3 = *(const float4*)&accbuf[3][r][c4];
        const float ps = psum_sh[0][r] + psum_sh[1][r] + psum_sh[2][r] + psum_sh[3][r];
        const float sc = mask[b * NN + n0 + r] / ps;
        float4 o;
        o.x = (s0.x + s1.x + s2.x + s3.x) * sc;
        o.y = (s0.y + s1.y + s2.y + s3.y) * sc;
        o.z = (s0.z + s1.z + s2.z + s3.z) * sc;
        o.w = (s0.w + s1.w + s2.w + s3.w) * sc;
        *(float4*)&out[((long)b * NN + n0 + r) * FF + c4] = o;
    }
}

// ---------------------------------------------------------------------------
extern "C" void kernel_launch(void* const* d_in, const int* in_sizes, int n_in,
                              void* d_out, int out_size, void* d_ws, size_t ws_size,
                              hipStream_t stream)
{
    const float* feat = (const float*)d_in[0];
    const int*   adj  = (const int*)d_in[1];
    const float* mask = (const float*)d_in[2];
    const float* W    = (const float*)d_in[3];
    const float* bias = (const float*)d_in[4];
    const float* a    = (const float*)d_in[5];
    float* out = (float*)d_out;

    // ws: htg bf16 [8][128][2048] (4MB) | esrc f32 64KB | edst f32 64KB | bm 4MB
    u16*   htg  = (u16*)d_ws;
    float* esrc = (float*)(htg + (size_t)BB * FF * NN);
    float* edst = esrc + BB * NN;
    u64*   bmp  = (u64*)(edst + BB * NN);

    k_pack<<<BB * NN / 8, 256, 0, stream>>>(adj, bmp);
    k_h   <<<BB * NN / 8, 256, 0, stream>>>(feat, W, bias, a, htg, esrc, edst);
    k_attn<<<BB * (NN / RB), 256, 0, stream>>>(bmp, mask, htg, esrc, edst, out);
}